// Round 8
// baseline (252.083 us; speedup 1.0000x reference)
//
#include <hip/hip_runtime.h>
#include <hip/hip_cooperative_groups.h>
#include <math.h>

namespace cg = cooperative_groups;

#define Bb 64
#define Ll 1024
#define Dd 512
#define Aa 512
#define NEG_INF -1e9f

#define LOG2E  1.4426950408889634f
#define LOG2E2 2.8853901617526703f   // 2*log2(e)
#define GRID   512

typedef float fx4 __attribute__((ext_vector_type(4)));

__device__ __forceinline__ float fast_exp2(float x) { return __builtin_amdgcn_exp2f(x); }
__device__ __forceinline__ float fast_rcp(float x)  { return __builtin_amdgcn_rcpf(x); }

#define TERMS(ACC, KA, KB, Q0, Q1, V0, V1)                                      \
    ACC = fmaf(V0.x, fast_rcp(fast_exp2(fmaf(KA.x, LOG2E2, Q0.x)) + 1.f), ACC); \
    ACC = fmaf(V0.y, fast_rcp(fast_exp2(fmaf(KA.y, LOG2E2, Q0.y)) + 1.f), ACC); \
    ACC = fmaf(V0.z, fast_rcp(fast_exp2(fmaf(KA.z, LOG2E2, Q0.z)) + 1.f), ACC); \
    ACC = fmaf(V0.w, fast_rcp(fast_exp2(fmaf(KA.w, LOG2E2, Q0.w)) + 1.f), ACC); \
    ACC = fmaf(V1.x, fast_rcp(fast_exp2(fmaf(KB.x, LOG2E2, Q1.x)) + 1.f), ACC); \
    ACC = fmaf(V1.y, fast_rcp(fast_exp2(fmaf(KB.y, LOG2E2, Q1.y)) + 1.f), ACC); \
    ACC = fmaf(V1.z, fast_rcp(fast_exp2(fmaf(KB.z, LOG2E2, Q1.z)) + 1.f), ACC); \
    ACC = fmaf(V1.w, fast_rcp(fast_exp2(fmaf(KB.w, LOG2E2, Q1.w)) + 1.f), ACC);

#define RED6(A)                    \
    A += __shfl_xor(A, 32);        \
    A += __shfl_xor(A, 16);        \
    A += __shfl_xor(A, 8);         \
    A += __shfl_xor(A, 4);         \
    A += __shfl_xor(A, 2);         \
    A += __shfl_xor(A, 1);

__global__ __launch_bounds__(256, 2) void k_fused(const float* __restrict__ key,
                                                  const float* __restrict__ noise,
                                                  const float* __restrict__ mask,
                                                  const float* __restrict__ prev,
                                                  const float* __restrict__ dh,
                                                  const float* __restrict__ W,
                                                  const float* __restrict__ bias,
                                                  const float* __restrict__ vw,
                                                  const float* __restrict__ vg,
                                                  const float* __restrict__ vb,
                                                  const float* __restrict__ r,
                                                  float* __restrict__ qb,
                                                  float* __restrict__ vv2,
                                                  float* __restrict__ scal,
                                                  float* __restrict__ p,
                                                  float* __restrict__ alpha) {
    cg::grid_group gg = cg::this_grid();
    __shared__ float h[Dd];
    __shared__ float red[4];
    __shared__ float wAB[8];

    const int bid = blockIdx.x;
    const int tid = threadIdx.x;
    const int wave = tid >> 6, lane = tid & 63;

    // ================= Phase 1: qb = dh @ W^T + bias; vv2, scal =================
    {
        const int b = bid >> 3;              // 8 blocks per b-row
        const int c = bid & 7;               // a-chunk of 64 rows
        const int a = c * 64 + (tid >> 2);
        const int quart = tid & 3;

        ((float2*)h)[tid] = ((const float2*)(dh + (size_t)b * Dd))[tid];
        __syncthreads();

        const float4* Wr = (const float4*)(W + (size_t)a * Dd + quart * 128);
        const float4* h4 = (const float4*)(h + quart * 128);
        float acc = 0.f;
        #pragma unroll 8
        for (int i = 0; i < 32; ++i) {
            float4 wq = Wr[i];
            float4 hv = h4[i];
            acc = fmaf(wq.x, hv.x, acc);
            acc = fmaf(wq.y, hv.y, acc);
            acc = fmaf(wq.z, hv.z, acc);
            acc = fmaf(wq.w, hv.w, acc);
        }
        acc += __shfl_xor(acc, 1);
        acc += __shfl_xor(acc, 2);
        if (quart == 0) qb[(size_t)b * Aa + a] = acc + bias[a];

        if (bid == 0) {
            float w0 = vw[tid], w1 = vw[tid + 256];
            float s = fmaf(w0, w0, w1 * w1);
            #pragma unroll
            for (int off = 32; off; off >>= 1) s += __shfl_xor(s, off);
            if (lane == 0) red[wave] = s;
            __syncthreads();
            float tot = red[0] + red[1] + red[2] + red[3];
            float inv = rsqrtf(tot);
            float g = vg[0];
            float vva0 = g * w0 * inv, vva1 = g * w1 * inv;
            vv2[tid] = 2.f * vva0;
            vv2[tid + 256] = 2.f * vva1;
            float s2 = vva0 + vva1;
            #pragma unroll
            for (int off = 32; off; off >>= 1) s2 += __shfl_xor(s2, off);
            __syncthreads();
            if (lane == 0) red[wave] = s2;
            __syncthreads();
            if (tid == 0)
                scal[0] = red[0] + red[1] + red[2] + red[3] + vb[0] + r[0];
        }
        __threadfence();
    }
    gg.sync();

    // ================= Phase 2: p = masked sigmoid(energy + noise) =================
    {
        const int b = bid >> 3;              // same b for both chunks of this block
        const int x0 = (bid & 7) * 2;        // first of 2 l-chunks (64 l each)

        const fx4* qb4 = (const fx4*)(qb + (size_t)b * Aa);
        fx4 q0 = qb4[lane];
        fx4 q1 = qb4[lane + 64];
        const fx4* v4 = (const fx4*)vv2;
        const fx4 v0 = v4[lane];
        const fx4 v1 = v4[lane + 64];
        const float ec = scal[0];
        q0 *= LOG2E2;
        q1 *= LOG2E2;

        const int lj = lane & 7;

        #pragma unroll 1
        for (int half = 0; half < 2; ++half) {
            const int lblk = (x0 + half) * 64;
            #pragma unroll 1
            for (int it = 0; it < 2; ++it) {
                const int lw0 = lblk + it * 32 + wave * 8;
                const int l = lw0 + lj;
                const float mk = mask[(size_t)b * Ll + l];
                const float nz = noise[(size_t)b * Ll + l];
                const float mn = (l == Ll - 1) ? 0.f : mask[(size_t)b * Ll + l + 1];

                const fx4* kp = (const fx4*)(key + ((size_t)b * Ll + lw0) * Aa);
                fx4 ka0 = kp[lane];           fx4 kb0 = kp[lane + 64];
                fx4 ka1 = kp[lane + 128];     fx4 kb1 = kp[lane + 192];
                fx4 ka2 = kp[lane + 256];     fx4 kb2 = kp[lane + 320];
                fx4 ka3 = kp[lane + 384];     fx4 kb3 = kp[lane + 448];
                fx4 ka4 = kp[lane + 512];     fx4 kb4 = kp[lane + 576];
                fx4 ka5 = kp[lane + 640];     fx4 kb5 = kp[lane + 704];
                fx4 ka6 = kp[lane + 768];     fx4 kb6 = kp[lane + 832];
                fx4 ka7 = kp[lane + 896];     fx4 kb7 = kp[lane + 960];
                __builtin_amdgcn_sched_barrier(0);

                float a0 = 0.f, a1 = 0.f, a2 = 0.f, a3 = 0.f,
                      a4 = 0.f, a5 = 0.f, a6 = 0.f, a7 = 0.f;
                TERMS(a0, ka0, kb0, q0, q1, v0, v1)
                TERMS(a1, ka1, kb1, q0, q1, v0, v1)
                TERMS(a2, ka2, kb2, q0, q1, v0, v1)
                TERMS(a3, ka3, kb3, q0, q1, v0, v1)
                TERMS(a4, ka4, kb4, q0, q1, v0, v1)
                TERMS(a5, ka5, kb5, q0, q1, v0, v1)
                TERMS(a6, ka6, kb6, q0, q1, v0, v1)
                TERMS(a7, ka7, kb7, q0, q1, v0, v1)

                RED6(a0) RED6(a1) RED6(a2) RED6(a3) RED6(a4) RED6(a5) RED6(a6) RED6(a7)

                float sel = a0;
                sel = (lj == 1) ? a1 : sel;
                sel = (lj == 2) ? a2 : sel;
                sel = (lj == 3) ? a3 : sel;
                sel = (lj == 4) ? a4 : sel;
                sel = (lj == 5) ? a5 : sel;
                sel = (lj == 6) ? a6 : sel;
                sel = (lj == 7) ? a7 : sel;

                float e = (mk > 0.f) ? (ec - sel) : NEG_INF;
                float z = e + nz;
                float pv = fast_rcp(1.f + fast_exp2(-z * LOG2E));
                float em = mk * (1.f - mn);
                if (em > 0.f) pv = em;
                if (lane < 8) p[(size_t)b * Ll + l] = pv;
                __builtin_amdgcn_sched_barrier(0);
            }
        }
        __threadfence();
    }
    gg.sync();

    // ================= Phase 3: alpha = p * linear_recurrence =================
    if (bid < Bb) {
        const int b = bid;
        const float* prow = p + (size_t)b * Ll;
        const float4 pp = ((const float4*)prow)[tid];
        const float4 pa = ((const float4*)(prev + (size_t)b * Ll))[tid];
        float pm1 = 0.f;
        if (tid) pm1 = prow[tid * 4 - 1];
        const float a0 = 1.f - pm1;
        const float a1 = 1.f - pp.x;
        const float a2 = 1.f - pp.y;
        const float a3 = 1.f - pp.z;

        float A = a0, Bv = pa.x;
        Bv = fmaf(a1, Bv, pa.y); A *= a1;
        Bv = fmaf(a2, Bv, pa.z); A *= a2;
        Bv = fmaf(a3, Bv, pa.w); A *= a3;

        float Ai = A, Bi = Bv;
        #pragma unroll
        for (int off = 1; off < 64; off <<= 1) {
            float qA = __shfl_up(Ai, off);
            float qB = __shfl_up(Bi, off);
            if (lane >= off) { Bi = fmaf(Ai, qB, Bi); Ai *= qA; }
        }
        float eA = __shfl_up(Ai, 1), eB = __shfl_up(Bi, 1);
        if (lane == 0) { eA = 1.f; eB = 0.f; }
        if (lane == 63) { wAB[wave] = Ai; wAB[4 + wave] = Bi; }
        __syncthreads();
        float bwe = 0.f;
        for (int w2 = 0; w2 < wave; ++w2) bwe = fmaf(wAB[w2], bwe, wAB[4 + w2]);
        float x = fmaf(eA, bwe, eB);

        float4 o;
        x = fmaf(a0, x, pa.x); o.x = pp.x * x;
        x = fmaf(a1, x, pa.y); o.y = pp.y * x;
        x = fmaf(a2, x, pa.z); o.z = pp.z * x;
        x = fmaf(a3, x, pa.w); o.w = pp.w * x;
        ((float4*)(alpha + (size_t)b * Ll))[tid] = o;
    }
}

extern "C" void kernel_launch(void* const* d_in, const int* in_sizes, int n_in,
                              void* d_out, int out_size, void* d_ws, size_t ws_size,
                              hipStream_t stream) {
    const float* dh    = (const float*)d_in[0];   // decoder_h [B,D]
    const float* key   = (const float*)d_in[1];   // key [B,L,A]
    // d_in[2] encoder_outputs — unused by the reference
    const float* prev  = (const float*)d_in[3];   // prev_att [B,L]
    const float* noise = (const float*)d_in[4];   // noise [B,L]
    const float* mask  = (const float*)d_in[5];   // mask [B,L]
    const float* W     = (const float*)d_in[6];   // W [A,D]
    const float* bias  = (const float*)d_in[7];   // b [A]
    const float* vw    = (const float*)d_in[8];   // v_weight [1,A]
    const float* vg    = (const float*)d_in[9];   // v_g [1]
    const float* vb    = (const float*)d_in[10];  // v_bias [1]
    const float* r     = (const float*)d_in[11];  // r [1]
    float* out = (float*)d_out;

    float* ws   = (float*)d_ws;
    float* vv2  = ws;                        // 512 floats
    float* scal = ws + Aa;                   // 1 float (padded to 1024)
    float* qb   = ws + 1024;                 // 64*512
    float* p    = ws + 1024 + Bb * Aa;       // 64*1024

    void* args[] = {(void*)&key, (void*)&noise, (void*)&mask, (void*)&prev,
                    (void*)&dh,  (void*)&W,     (void*)&bias, (void*)&vw,
                    (void*)&vg,  (void*)&vb,    (void*)&r,
                    (void*)&qb,  (void*)&vv2,   (void*)&scal, (void*)&p, (void*)&out};
    hipLaunchCooperativeKernel(reinterpret_cast<void*>(k_fused),
                               dim3(GRID), dim3(256), args, 0, stream);
}

// Round 9
// 48.023 us; speedup vs baseline: 5.2492x; 5.2492x over previous
//
#include <hip/hip_runtime.h>
#include <math.h>

#define Bb 64
#define Ll 1024
#define Dd 512
#define Aa 512
#define NEG_INF -1e9f

#define LOG2E  1.4426950408889634f
#define LOG2E2 2.8853901617526703f   // 2*log2(e)
#define NCH 8                        // a-chunks of 64

typedef float fx4 __attribute__((ext_vector_type(4)));

__device__ __forceinline__ float fast_exp2(float x) { return __builtin_amdgcn_exp2f(x); }
__device__ __forceinline__ float fast_rcp(float x)  { return __builtin_amdgcn_rcpf(x); }

// ---------------- K_A: partial energies ----------------
// grid (NCH, 2, Bb), 256 thr. Block computes q for its 64-a chunk, then streams
// key[b, lhalf*512 .. +512, c*64 .. +64] and writes pw[b][l][c] partial sums.
__global__ __launch_bounds__(256) void k_epart(const float* __restrict__ key,
                                               const float* __restrict__ dh,
                                               const float* __restrict__ W,
                                               const float* __restrict__ bias,
                                               const float* __restrict__ vw,
                                               const float* __restrict__ vg,
                                               float* __restrict__ pw) {
    const int c     = blockIdx.x;        // a-chunk (64 wide)
    const int halfl = blockIdx.y;        // l half (512 rows)
    const int b     = blockIdx.z;
    const int tid   = threadIdx.x;
    const int wave  = tid >> 6, lane = tid & 63;

    __shared__ float h[Dd];
    __shared__ float qs[64];
    __shared__ float vs[64];
    __shared__ float red[4];

    ((float2*)h)[tid] = ((const float2*)(dh + (size_t)b * Dd))[tid];

    // ||v||^2 (redundant per block)
    {
        float w0 = vw[tid], w1 = vw[tid + 256];
        float s = fmaf(w0, w0, w1 * w1);
        #pragma unroll
        for (int off = 32; off; off >>= 1) s += __shfl_xor(s, off);
        if (lane == 0) red[wave] = s;
    }
    __syncthreads();
    const float inv = rsqrtf(red[0] + red[1] + red[2] + red[3]);
    const float g2 = 2.f * vg[0];

    // q for rows c*64 .. c*64+63 (4 threads per row)
    {
        const int r = tid >> 2, quart = tid & 3;
        const int arow = c * 64 + r;
        const float4* Wr = (const float4*)(W + (size_t)arow * Dd + quart * 128);
        const float4* h4 = (const float4*)(h + quart * 128);
        float acc = 0.f;
        #pragma unroll 8
        for (int i = 0; i < 32; ++i) {
            float4 wq = Wr[i];
            float4 hv = h4[i];
            acc = fmaf(wq.x, hv.x, acc);
            acc = fmaf(wq.y, hv.y, acc);
            acc = fmaf(wq.z, hv.z, acc);
            acc = fmaf(wq.w, hv.w, acc);
        }
        acc += __shfl_xor(acc, 1);
        acc += __shfl_xor(acc, 2);
        if (quart == 0) {
            qs[r] = (acc + bias[arow]) * LOG2E2;   // pre-scaled
            vs[r] = g2 * vw[arow] * inv;           // = 2*vv
        }
    }
    __syncthreads();

    // each 8-lane group owns one l-row; lane's 8 a-elems = two 4-elem halves
    const int sub = lane & 7;
    fx4 q0 = *(const fx4*)&qs[sub * 4];
    fx4 q1 = *(const fx4*)&qs[32 + sub * 4];
    fx4 v0 = *(const fx4*)&vs[sub * 4];
    fx4 v1 = *(const fx4*)&vs[32 + sub * 4];

    const int lbase = halfl * 512 + wave * 8 + (lane >> 3);
    const float* rowp = key + ((size_t)b * Ll + lbase) * Aa + c * 64;
    float* pwp = pw + (((size_t)b * Ll + lbase) * NCH) + c;

    #pragma unroll 4
    for (int it = 0; it < 16; ++it) {
        const float* rp = rowp + (size_t)it * 32 * Aa;
        fx4 ka = *(const fx4*)(rp + sub * 4);          // dense 128B across 8 lanes
        fx4 kb = *(const fx4*)(rp + 32 + sub * 4);     // second 128B half

        float acc = 0.f;
        acc = fmaf(v0.x, fast_rcp(fast_exp2(fmaf(ka.x, LOG2E2, q0.x)) + 1.f), acc);
        acc = fmaf(v0.y, fast_rcp(fast_exp2(fmaf(ka.y, LOG2E2, q0.y)) + 1.f), acc);
        acc = fmaf(v0.z, fast_rcp(fast_exp2(fmaf(ka.z, LOG2E2, q0.z)) + 1.f), acc);
        acc = fmaf(v0.w, fast_rcp(fast_exp2(fmaf(ka.w, LOG2E2, q0.w)) + 1.f), acc);
        acc = fmaf(v1.x, fast_rcp(fast_exp2(fmaf(kb.x, LOG2E2, q1.x)) + 1.f), acc);
        acc = fmaf(v1.y, fast_rcp(fast_exp2(fmaf(kb.y, LOG2E2, q1.y)) + 1.f), acc);
        acc = fmaf(v1.z, fast_rcp(fast_exp2(fmaf(kb.z, LOG2E2, q1.z)) + 1.f), acc);
        acc = fmaf(v1.w, fast_rcp(fast_exp2(fmaf(kb.w, LOG2E2, q1.w)) + 1.f), acc);

        acc += __shfl_xor(acc, 1);
        acc += __shfl_xor(acc, 2);
        acc += __shfl_xor(acc, 4);
        if (sub == 0) pwp[(size_t)it * 32 * NCH] = acc;
    }
}

// ---------------- K_B: reduce partials + sigmoid + scan ----------------
// grid (Bb), 256 thr. Thread handles 4 consecutive l. p lives in registers.
__global__ __launch_bounds__(256) void k_finish(const float* __restrict__ pw,
                                                const float* __restrict__ noise,
                                                const float* __restrict__ mask,
                                                const float* __restrict__ prev,
                                                const float* __restrict__ vw,
                                                const float* __restrict__ vg,
                                                const float* __restrict__ vb,
                                                const float* __restrict__ r,
                                                float* __restrict__ alpha) {
    const int b = blockIdx.x;
    const int tid = threadIdx.x;
    const int wave = tid >> 6, lane = tid & 63;
    __shared__ float red[4], red2[4], pend[4], wA[4], wB[4];

    // ec = sum(vv) + vbias + r, redundant per block
    {
        float w0 = vw[tid], w1 = vw[tid + 256];
        float s = fmaf(w0, w0, w1 * w1);
        float t = w0 + w1;
        #pragma unroll
        for (int off = 32; off; off >>= 1) {
            s += __shfl_xor(s, off);
            t += __shfl_xor(t, off);
        }
        if (lane == 0) { red[wave] = s; red2[wave] = t; }
    }
    __syncthreads();
    const float inv = rsqrtf(red[0] + red[1] + red[2] + red[3]);
    const float sumv = red2[0] + red2[1] + red2[2] + red2[3];
    const float ec = vg[0] * inv * sumv + vb[0] + r[0];

    const int l0 = tid * 4;
    const float* pwb = pw + ((size_t)b * Ll + l0) * NCH;
    fx4 s0a = *(const fx4*)(pwb + 0),  s0b = *(const fx4*)(pwb + 4);
    fx4 s1a = *(const fx4*)(pwb + 8),  s1b = *(const fx4*)(pwb + 12);
    fx4 s2a = *(const fx4*)(pwb + 16), s2b = *(const fx4*)(pwb + 20);
    fx4 s3a = *(const fx4*)(pwb + 24), s3b = *(const fx4*)(pwb + 28);
    float e0 = ((s0a.x + s0a.y) + (s0a.z + s0a.w)) + ((s0b.x + s0b.y) + (s0b.z + s0b.w));
    float e1 = ((s1a.x + s1a.y) + (s1a.z + s1a.w)) + ((s1b.x + s1b.y) + (s1b.z + s1b.w));
    float e2 = ((s2a.x + s2a.y) + (s2a.z + s2a.w)) + ((s2b.x + s2b.y) + (s2b.z + s2b.w));
    float e3 = ((s3a.x + s3a.y) + (s3a.z + s3a.w)) + ((s3b.x + s3b.y) + (s3b.z + s3b.w));

    const float4 nz = ((const float4*)(noise + (size_t)b * Ll))[tid];
    const float4 mk = ((const float4*)(mask + (size_t)b * Ll))[tid];
    const float mk4 = (tid == 255) ? 0.f : mask[(size_t)b * Ll + l0 + 4];

    float4 pp;
    {
        float e, z, pv, em;
        e = (mk.x > 0.f) ? (ec - e0) : NEG_INF; z = e + nz.x;
        pv = fast_rcp(1.f + fast_exp2(-z * LOG2E));
        em = mk.x * (1.f - mk.y); pp.x = (em > 0.f) ? em : pv;
        e = (mk.y > 0.f) ? (ec - e1) : NEG_INF; z = e + nz.y;
        pv = fast_rcp(1.f + fast_exp2(-z * LOG2E));
        em = mk.y * (1.f - mk.z); pp.y = (em > 0.f) ? em : pv;
        e = (mk.z > 0.f) ? (ec - e2) : NEG_INF; z = e + nz.z;
        pv = fast_rcp(1.f + fast_exp2(-z * LOG2E));
        em = mk.z * (1.f - mk.w); pp.z = (em > 0.f) ? em : pv;
        e = (mk.w > 0.f) ? (ec - e3) : NEG_INF; z = e + nz.w;
        pv = fast_rcp(1.f + fast_exp2(-z * LOG2E));
        em = mk.w * (1.f - mk4); pp.w = (em > 0.f) ? em : pv;
    }

    if (lane == 63) pend[wave] = pp.w;
    __syncthreads();
    float pm1 = __shfl_up(pp.w, 1);
    if (lane == 0) pm1 = (wave == 0) ? 0.f : pend[wave - 1];

    const float4 pa = ((const float4*)(prev + (size_t)b * Ll))[tid];
    const float a0 = 1.f - pm1;
    const float a1 = 1.f - pp.x;
    const float a2 = 1.f - pp.y;
    const float a3 = 1.f - pp.z;

    float A = a0, Bv = pa.x;
    Bv = fmaf(a1, Bv, pa.y); A *= a1;
    Bv = fmaf(a2, Bv, pa.z); A *= a2;
    Bv = fmaf(a3, Bv, pa.w); A *= a3;

    float Ai = A, Bi = Bv;
    #pragma unroll
    for (int off = 1; off < 64; off <<= 1) {
        float qA = __shfl_up(Ai, off);
        float qB = __shfl_up(Bi, off);
        if (lane >= off) { Bi = fmaf(Ai, qB, Bi); Ai *= qA; }
    }
    float eA = __shfl_up(Ai, 1), eB = __shfl_up(Bi, 1);
    if (lane == 0) { eA = 1.f; eB = 0.f; }
    if (lane == 63) { wA[wave] = Ai; wB[wave] = Bi; }
    __syncthreads();
    float bwe = 0.f;
    for (int w2 = 0; w2 < wave; ++w2) bwe = fmaf(wA[w2], bwe, wB[w2]);
    float x = fmaf(eA, bwe, eB);

    float4 o;
    x = fmaf(a0, x, pa.x); o.x = pp.x * x;
    x = fmaf(a1, x, pa.y); o.y = pp.y * x;
    x = fmaf(a2, x, pa.z); o.z = pp.z * x;
    x = fmaf(a3, x, pa.w); o.w = pp.w * x;
    ((float4*)(alpha + (size_t)b * Ll))[tid] = o;
}

extern "C" void kernel_launch(void* const* d_in, const int* in_sizes, int n_in,
                              void* d_out, int out_size, void* d_ws, size_t ws_size,
                              hipStream_t stream) {
    const float* dh    = (const float*)d_in[0];   // decoder_h [B,D]
    const float* key   = (const float*)d_in[1];   // key [B,L,A]
    // d_in[2] encoder_outputs — unused by the reference
    const float* prev  = (const float*)d_in[3];   // prev_att [B,L]
    const float* noise = (const float*)d_in[4];   // noise [B,L]
    const float* mask  = (const float*)d_in[5];   // mask [B,L]
    const float* W     = (const float*)d_in[6];   // W [A,D]
    const float* bias  = (const float*)d_in[7];   // b [A]
    const float* vw    = (const float*)d_in[8];   // v_weight [1,A]
    const float* vg    = (const float*)d_in[9];   // v_g [1]
    const float* vb    = (const float*)d_in[10];  // v_bias [1]
    const float* r     = (const float*)d_in[11];  // r [1]
    float* out = (float*)d_out;

    float* pw = (float*)d_ws;                     // [64][1024][8] f32 = 2 MB

    k_epart<<<dim3(NCH, 2, Bb), 256, 0, stream>>>(key, dh, W, bias, vw, vg, pw);
    k_finish<<<Bb, 256, 0, stream>>>(pw, noise, mask, prev, vw, vg, vb, r, out);
}